// Round 1
// 448.781 us; speedup vs baseline: 1.0556x; 1.0556x over previous
//
#include <hip/hip_runtime.h>
#include <hip/hip_bf16.h>

#define B_ 4
#define L_ 2052
#define C_ 1024
#define H_ 16
#define D_ 64
#define NREG_ 4
#define M_ (B_*L_)     // 8208
#define LP_ 2056       // padded L stride for Vt (16B-aligned rows)
#define QSC 0.18033688f  // 0.125 * log2(e), applied in fp32 inside attn

typedef short bf16x8 __attribute__((ext_vector_type(8)));
typedef float f32x4 __attribute__((ext_vector_type(4)));
typedef __hip_bfloat16 bf16;

#define MFMA(a,b,c) __builtin_amdgcn_mfma_f32_16x16x32_bf16(a,b,c,0,0,0)

__device__ inline float b2f(bf16 v){ return __bfloat162float(v); }
__device__ inline bf16  f2b(float v){ return __float2bfloat16(v); }
__device__ inline bf16x8 as8(int4 v){ union{int4 i; bf16x8 b;} u; u.i=v; return u.b; }

// ---------------- x -> bf16 hi/lo split ----------------
__global__ __launch_bounds__(256)
void cvt_split(const float* __restrict__ in, bf16* __restrict__ hi,
               bf16* __restrict__ lo, int n)
{
    int i = (blockIdx.x*256 + threadIdx.x)*4;
    if (i >= n) return;
    float4 v = *(const float4*)(in + i);
    int2 hraw, lraw;
    bf16* hp = (bf16*)&hraw;
    bf16* lp = (bf16*)&lraw;
    float vv[4] = {v.x, v.y, v.z, v.w};
    #pragma unroll
    for (int j=0;j<4;++j){
        bf16 h = f2b(vv[j]);
        hp[j] = h;
        lp[j] = f2b(vv[j] - b2f(h));
    }
    *(int2*)(hi + i) = hraw;
    *(int2*)(lo + i) = lraw;
}

// ---------------- fp32 [R][Cc] -> bf16 transposed [Cc][R] ----------------
__global__ __launch_bounds__(256)
void transpose_cvt(const float* __restrict__ in, bf16* __restrict__ out,
                   int R, int Cc)
{
    __shared__ bf16 t[32][33];
    int bx = blockIdx.x * 32;
    int by = blockIdx.y * 32;
    int tx = threadIdx.x;
    int ty = threadIdx.y;
    #pragma unroll
    for (int i=0;i<4;++i){
        int r = by + ty + i*8;
        int c = bx + tx;
        t[ty+i*8][tx] = f2b(in[(size_t)r*Cc + c]);
    }
    __syncthreads();
    #pragma unroll
    for (int i=0;i<4;++i){
        int r = bx + ty + i*8;
        int c = by + tx;
        out[(size_t)r*R + c] = t[tx][ty+i*8];
    }
}

// ---- GEMM, block tile 128x256, wave tile 64x128 (mi4 x ni8) ----
// A[M][K] (+optional lo) x Bt[N][K] -> C[M][N] + bias. N%256==0, K%32==0.
template<typename OutT, bool SPLIT>
__global__ __launch_bounds__(256,2)
void gemm_wide(const bf16* __restrict__ A, const bf16* __restrict__ Alo,
               const bf16* __restrict__ Bt, const float* __restrict__ bias,
               OutT* __restrict__ C, int M, int N, int K)
{
    __shared__ bf16 As[128*40];
    __shared__ bf16 Als[SPLIT ? 128*40 : 8];
    __shared__ bf16 Bs[256*40];

    int tid  = threadIdx.x;
    int lane = tid & 63, wave = tid >> 6;
    int wm = (wave>>1)*64, wn = (wave&1)*128;
    int bm = blockIdx.y*128, bn = blockIdx.x*256;
    int lrow = lane & 15, lk8 = (lane>>4)*8;
    int quad = lane >> 4;

    f32x4 acc[4][8] = {};

    int r0 = tid >> 2;          // 0..63
    int c0 = (tid & 3) * 8;     // 0,8,16,24

    for (int k0 = 0; k0 < K; k0 += 32) {
        #pragma unroll
        for (int it=0; it<2; ++it) {
            int r = r0 + it*64;
            int ga = bm + r;
            int4 va = {0,0,0,0}, vl = {0,0,0,0};
            if (ga < M) {
                va = *(const int4*)(A + (size_t)ga*K + k0 + c0);
                if constexpr (SPLIT)
                    vl = *(const int4*)(Alo + (size_t)ga*K + k0 + c0);
            }
            *(int4*)(&As[r*40 + c0]) = va;
            if constexpr (SPLIT) *(int4*)(&Als[r*40 + c0]) = vl;
        }
        #pragma unroll
        for (int it=0; it<4; ++it) {
            int r = r0 + it*64;
            int4 vb = *(const int4*)(Bt + (size_t)(bn + r)*K + k0 + c0);
            *(int4*)(&Bs[r*40 + c0]) = vb;
        }
        __syncthreads();

        bf16x8 b[8];
        #pragma unroll
        for (int i=0;i<8;++i)
            b[i] = *(const bf16x8*)(&Bs[(wn+i*16+lrow)*40 + lk8]);
        #pragma unroll
        for (int mi=0;mi<4;++mi){
            bf16x8 a = *(const bf16x8*)(&As[(wm+mi*16+lrow)*40 + lk8]);
            #pragma unroll
            for (int ni=0;ni<8;++ni)
                acc[mi][ni] = MFMA(a, b[ni], acc[mi][ni]);
            if constexpr (SPLIT) {
                bf16x8 al = *(const bf16x8*)(&Als[(wm+mi*16+lrow)*40 + lk8]);
                #pragma unroll
                for (int ni=0;ni<8;++ni)
                    acc[mi][ni] = MFMA(al, b[ni], acc[mi][ni]);
            }
        }
        __syncthreads();
    }

    #pragma unroll
    for (int ni=0;ni<8;++ni){
        int col = bn + wn + ni*16 + lrow;
        float bv = bias[col];
        #pragma unroll
        for (int mi=0;mi<4;++mi){
            int rowb = bm + wm + mi*16 + quad*4;
            #pragma unroll
            for (int r=0;r<4;++r){
                int row = rowb + r;
                if (row < M) {
                    float v = acc[mi][ni][r] + bv;
                    if constexpr (sizeof(OutT)==4) C[(size_t)row*N + col] = v;
                    else                           C[(size_t)row*N + col] = f2b(v);
                }
            }
        }
    }
}

// ---------------- RoPE in-place on q,k (pure rotation) ----------------
__global__ __launch_bounds__(256)
void rope_kernel(bf16* __restrict__ qkv, const float* __restrict__ rope)
{
    int idx = blockIdx.x*256 + threadIdx.x;
    int d = idx & 31;
    int h = (idx >> 5) & 15;
    int m = idx >> 9;
    if (m >= M_) return;
    int l = m % L_;
    if (l < NREG_) return;
    const float* cp = rope + (size_t)(l - NREG_)*D_;
    const float* sp = rope + (size_t)(L_ - NREG_)*D_ + (size_t)(l - NREG_)*D_;
    float c0 = cp[d], c1 = cp[d+32], s0 = sp[d], s1 = sp[d+32];
    size_t base = (size_t)m*3072 + h*64;
    {
        float a = b2f(qkv[base + d]), b = b2f(qkv[base + d + 32]);
        qkv[base + d]      = f2b(a*c0 - b*s0);
        qkv[base + d + 32] = f2b(b*c1 + a*s1);
    }
    {
        size_t kb = base + 1024;
        float a = b2f(qkv[kb + d]), b = b2f(qkv[kb + d + 32]);
        qkv[kb + d]      = f2b(a*c0 - b*s0);
        qkv[kb + d + 32] = f2b(b*c1 + a*s1);
    }
}

// ---------------- V -> Vt [B*H][D][LP_] (zero-padded cols) ----------------
__global__ __launch_bounds__(256)
void transpose_v(const bf16* __restrict__ qkv, bf16* __restrict__ Vt)
{
    __shared__ bf16 t[64*72];
    int bh = blockIdx.y, lt = blockIdx.x;
    int b = bh >> 4, h = bh & 15;
    int tid = threadIdx.x;
    #pragma unroll
    for (int it=0; it<2; ++it){
        int i = tid + it*256;
        int il = i >> 3, c = (i&7)*8;
        int l = lt*64 + il;
        int4 v = {0,0,0,0};
        if (l < L_) v = *(const int4*)(qkv + ((size_t)b*L_ + l)*3072 + 2048 + h*64 + c);
        *(int4*)(&t[il*72 + c]) = v;
    }
    __syncthreads();
    #pragma unroll
    for (int it=0; it<2; ++it){
        int i = tid + it*256;
        int d = i >> 3, ck = (i&7)*8;
        if (lt*64 + ck + 8 <= LP_){
            union { int4 q; bf16 e[8]; } u;
            #pragma unroll
            for (int j=0;j<8;++j) u.e[j] = t[(ck+j)*72 + d];
            *(int4*)(&Vt[((size_t)bh*64 + d)*LP_ + lt*64 + ck]) = u.q;
        }
    }
}

// ---------------- flash attention (round-9: register-resident P) ----------------
// Key idea: PV is computed operand-swapped, MFMA(V^T-frag, P-as-B-frag), so the
// softmax tile feeds PV directly from registers. K rows are staged into sK in a
// permuted slot order (slot = s*32+j*16+a*4+r for key = s*32+a*8+j*4+r) so that
// two consecutive QK^T tiles deposit exactly the 8 contiguous keys each lane's
// B-fragment needs, lane-locally: zero LDS traffic and zero cross-lane ops for P.
// Softmax denominator = MFMA(ones, P): output layout (col = lane&15 = q) matches
// the O^T accumulator exactly, so normalization is one scalar per lane.
__global__ __launch_bounds__(256)
void attn_kernel(const bf16* __restrict__ qkv, const bf16* __restrict__ Vt,
                 float* __restrict__ out)
{
    __shared__ bf16 sQ[128*72];   // Q tile [128][72]
    __shared__ bf16 sK[64*72];    // [key-slot][d], rows permuted
    __shared__ bf16 sV[64*72];    // [d][key]

    int tid = threadIdx.x, lane = tid & 63, wave = tid >> 6;
    int lrow = lane & 15, lk8 = (lane>>4)*8, quad = lane >> 4;
    int qt = blockIdx.x, bh = blockIdx.y;
    int b  = bh >> 4, h = bh & 15;
    size_t rowbase = (size_t)b * L_;
    int q0 = qt * 128;

    #pragma unroll
    for (int it=0; it<4; ++it){
        int i = tid + it*256;
        int r = i >> 3;
        int c = (i & 7) * 8;
        int lq = q0 + r;
        int4 v = {0,0,0,0};
        if (lq < L_) v = *(const int4*)(qkv + (rowbase + lq)*3072 + h*64 + c);
        *(int4*)(&sQ[r*72 + c]) = v;
    }
    __syncthreads();

    bf16x8 qf[2][2];
    #pragma unroll
    for (int qi=0;qi<2;++qi)
        #pragma unroll
        for (int s=0;s<2;++s)
            qf[qi][s] = *(const bf16x8*)(&sQ[(wave*32 + qi*16 + lrow)*72 + s*32 + lk8]);

    f32x4 o_[2][4] = {};
    f32x4 lsum[2] = {};

    bf16x8 onesf;
    #pragma unroll
    for (int j=0;j<8;++j) onesf[j] = (short)0x3F80;   // bf16 1.0

    const int nkt = (L_ + 63) / 64;   // 33

    int4 kr[2], vr[2];
    {
        #pragma unroll
        for (int it=0; it<2; ++it){
            int i = tid + it*256;
            int r = i >> 3, c = (i & 7)*8;
            int pr = (r & 0x23) | ((r & 0x0C) << 1) | ((r & 0x10) >> 2); // slot->key
            kr[it] = *(const int4*)(qkv + (rowbase + pr)*3072 + 1024 + h*64 + c);
            vr[it] = *(const int4*)(Vt + ((size_t)bh*64 + r)*LP_ + c);
        }
    }

    for (int kt = 0; kt < nkt; ++kt) {
        __syncthreads();
        #pragma unroll
        for (int it=0; it<2; ++it){
            int i = tid + it*256;
            int r = i >> 3, c = (i & 7)*8;
            *(int4*)(&sK[r*72 + c]) = kr[it];
            *(int4*)(&sV[r*72 + c]) = vr[it];
        }
        __syncthreads();
        if (kt+1 < nkt){
            #pragma unroll
            for (int it=0; it<2; ++it){
                int i = tid + it*256;
                int r = i >> 3, c = (i & 7)*8;
                int pr = (r & 0x23) | ((r & 0x0C) << 1) | ((r & 0x10) >> 2);
                int lk = (kt+1)*64 + pr;
                kr[it] = (lk < L_) ? *(const int4*)(qkv + (rowbase+lk)*3072 + 1024 + h*64 + c)
                                   : (int4){0,0,0,0};
                int vc = (kt+1)*64 + c;
                vr[it] = (vc + 8 <= LP_) ? *(const int4*)(Vt + ((size_t)bh*64 + r)*LP_ + vc)
                                         : (int4){0,0,0,0};
            }
        }

        bool full = (kt != 32);
        int4 pb[2][2];   // P as B-fragments: [qi][s], lane-local 8 keys each

        #pragma unroll
        for (int ki=0; ki<4; ++ki){
            bf16x8 kf0 = *(const bf16x8*)(&sK[(ki*16+lrow)*72 + lk8]);
            bf16x8 kf1 = *(const bf16x8*)(&sK[(ki*16+lrow)*72 + 32 + lk8]);
            #pragma unroll
            for (int qi=0; qi<2; ++qi){
                f32x4 t = {};
                t = MFMA(kf0, qf[qi][0], t);
                t = MFMA(kf1, qf[qi][1], t);
                float p[4];
                #pragma unroll
                for (int r=0;r<4;++r){
                    float e = __builtin_amdgcn_exp2f(t[r]*QSC);
                    // actual key index under permuted staging:
                    int keyi = (ki>>1)*32 + quad*8 + (ki&1)*4 + r;
                    p[r] = (full || (2048 + keyi) < L_) ? e : 0.f;
                }
                union { int2 d2; __hip_bfloat162 h2[2]; } u;
                u.h2[0] = __float22bfloat162_rn({p[0], p[1]});
                u.h2[1] = __float22bfloat162_rn({p[2], p[3]});
                if ((ki & 1) == 0){ pb[qi][ki>>1].x = u.d2.x; pb[qi][ki>>1].y = u.d2.y; }
                else              { pb[qi][ki>>1].z = u.d2.x; pb[qi][ki>>1].w = u.d2.y; }
            }
        }

        #pragma unroll
        for (int ni=0; ni<4; ++ni){
            bf16x8 vf0 = *(const bf16x8*)(&sV[(ni*16+lrow)*72 + lk8]);
            bf16x8 vf1 = *(const bf16x8*)(&sV[(ni*16+lrow)*72 + 32 + lk8]);
            #pragma unroll
            for (int mi=0; mi<2; ++mi){
                f32x4 t = o_[mi][ni];
                t = MFMA(vf0, as8(pb[mi][0]), t);
                t = MFMA(vf1, as8(pb[mi][1]), t);
                o_[mi][ni] = t;
            }
        }
        #pragma unroll
        for (int mi=0; mi<2; ++mi){
            lsum[mi] = MFMA(onesf, as8(pb[mi][0]), lsum[mi]);
            lsum[mi] = MFMA(onesf, as8(pb[mi][1]), lsum[mi]);
        }
    }

    // O^T layout: lane holds q = lane&15 (within mi group), d = ni*16 + quad*4 + r
    #pragma unroll
    for (int mi=0; mi<2; ++mi){
        float inv = 1.f / lsum[mi][0];
        int lq = q0 + wave*32 + mi*16 + lrow;
        if (lq < L_){
            size_t base = (rowbase + lq)*1024 + h*64;
            #pragma unroll
            for (int ni=0; ni<4; ++ni){
                f32x4 t = o_[mi][ni];
                float4 w = {t[0]*inv, t[1]*inv, t[2]*inv, t[3]*inv};
                *(float4*)(&out[base + ni*16 + quad*4]) = w;
            }
        }
    }
}

// ---------------- LayerNorm (fp32 in) -> bf16 ----------------
__global__ __launch_bounds__(256)
void ln_kernel(const float* __restrict__ in, const float* __restrict__ gamma,
               const float* __restrict__ beta, bf16* __restrict__ y)
{
    int row = blockIdx.x;
    int tid = threadIdx.x;
    int wave = tid >> 6, lane = tid & 63;
    float4 v4 = *(const float4*)(in + (size_t)row*1024 + tid*4);
    float v[4] = {v4.x, v4.y, v4.z, v4.w};
    float s = 0.f, q = 0.f;
    #pragma unroll
    for (int j=0;j<4;++j){ s += v[j]; q += v[j]*v[j]; }
    #pragma unroll
    for (int o=1;o<64;o<<=1){ s += __shfl_xor(s, o); q += __shfl_xor(q, o); }
    __shared__ float sh[8];
    if (lane == 0){ sh[wave] = s; sh[4+wave] = q; }
    __syncthreads();
    s = sh[0]+sh[1]+sh[2]+sh[3];
    q = sh[4]+sh[5]+sh[6]+sh[7];
    float mu  = s * (1.f/1024.f);
    float var = q * (1.f/1024.f) - mu*mu;
    float rstd = rsqrtf(var + 1e-5f);
    int2 raw;
    bf16* ob = (bf16*)&raw;
    #pragma unroll
    for (int j=0;j<4;++j){
        float g = gamma[tid*4+j], be = beta[tid*4+j];
        ob[j] = f2b((v[j]-mu)*rstd*g + be);
    }
    *(int2*)(y + (size_t)row*1024 + tid*4) = raw;
}

// ---------------- launch ----------------
extern "C" void kernel_launch(void* const* d_in, const int* in_sizes, int n_in,
                              void* d_out, int out_size, void* d_ws, size_t ws_size,
                              hipStream_t stream)
{
    const float* x     = (const float*)d_in[0];
    const float* rope  = (const float*)d_in[1];
    const float* Wqkv  = (const float*)d_in[2];
    const float* bqkv  = (const float*)d_in[3];
    const float* Wproj = (const float*)d_in[4];
    const float* bproj = (const float*)d_in[5];
    const float* lng   = (const float*)d_in[6];
    const float* lnb   = (const float*)d_in[7];
    float* out = (float*)d_out;

    char* ws = (char*)d_ws;
    size_t off = 0;
    auto alloc = [&](size_t bytes)->char* {
        char* p = ws + off;
        off += (bytes + 255) & ~(size_t)255;
        return p;
    };
    bf16* xhi    = (bf16*)alloc((size_t)M_*C_*2);
    bf16* xlo    = (bf16*)alloc((size_t)M_*C_*2);
    bf16* WqkvT  = (bf16*)alloc((size_t)3*C_*C_*2);
    bf16* WprojT = (bf16*)alloc((size_t)C_*C_*2);
    bf16* qkv    = (bf16*)alloc((size_t)M_*3*C_*2);
    bf16* Vt     = (bf16*)alloc((size_t)B_*H_*D_*LP_*2);

    float* attnF = (float*)xhi;        // xhi+xlo region = exactly M*C*4 bytes
    bf16*  y     = qkv;                // qkv dead after attention

    cvt_split<<<M_*C_/1024, 256, 0, stream>>>(x, xhi, xlo, M_*C_);
    transpose_cvt<<<dim3(3*C_/32, C_/32), dim3(32,8), 0, stream>>>(Wqkv, WqkvT, C_, 3*C_);
    transpose_cvt<<<dim3(C_/32, C_/32), dim3(32,8), 0, stream>>>(Wproj, WprojT, C_, C_);
    gemm_wide<bf16, true><<<dim3(3*C_/256, (M_+127)/128), 256, 0, stream>>>(
        xhi, xlo, WqkvT, bqkv, qkv, M_, 3*C_, C_);
    rope_kernel<<<(M_*H_*32)/256, 256, 0, stream>>>(qkv, rope);
    transpose_v<<<dim3((L_+63)/64, B_*H_), 256, 0, stream>>>(qkv, Vt);
    attn_kernel<<<dim3((L_+127)/128, B_*H_), 256, 0, stream>>>(qkv, Vt, attnF);
    ln_kernel<<<M_, 256, 0, stream>>>(attnF, lng, lnb, y);
    gemm_wide<float, false><<<dim3(C_/256, (M_+127)/128), 256, 0, stream>>>(
        y, nullptr, WprojT, bproj, out, M_, C_, C_);
}

// Round 2
// 434.575 us; speedup vs baseline: 1.0901x; 1.0327x over previous
//
#include <hip/hip_runtime.h>
#include <hip/hip_bf16.h>

#define B_ 4
#define L_ 2052
#define C_ 1024
#define H_ 16
#define D_ 64
#define NREG_ 4
#define M_ (B_*L_)     // 8208
#define LP_ 2056       // padded L stride for Vt (16B-aligned rows)
#define QSC 0.18033688f  // 0.125 * log2(e), applied in fp32 inside attn

typedef short bf16x8 __attribute__((ext_vector_type(8)));
typedef float f32x4 __attribute__((ext_vector_type(4)));
typedef __hip_bfloat16 bf16;

#define MFMA(a,b,c) __builtin_amdgcn_mfma_f32_16x16x32_bf16(a,b,c,0,0,0)

__device__ inline float b2f(bf16 v){ return __bfloat162float(v); }
__device__ inline bf16  f2b(float v){ return __float2bfloat16(v); }
__device__ inline bf16x8 as8(int4 v){ union{int4 i; bf16x8 b;} u; u.i=v; return u.b; }

// async global->LDS, 16B per lane; LDS dest = wave-uniform base + lane*16
__device__ inline void gl_lds16(const void* g, void* l){
    __builtin_amdgcn_global_load_lds(
        (const __attribute__((address_space(1))) void*)g,
        (__attribute__((address_space(3))) void*)l,
        16, 0, 0);
}

// ---------------- x -> bf16 hi/lo split ----------------
__global__ __launch_bounds__(256)
void cvt_split(const float* __restrict__ in, bf16* __restrict__ hi,
               bf16* __restrict__ lo, int n)
{
    int i = (blockIdx.x*256 + threadIdx.x)*4;
    if (i >= n) return;
    float4 v = *(const float4*)(in + i);
    int2 hraw, lraw;
    bf16* hp = (bf16*)&hraw;
    bf16* lp = (bf16*)&lraw;
    float vv[4] = {v.x, v.y, v.z, v.w};
    #pragma unroll
    for (int j=0;j<4;++j){
        bf16 h = f2b(vv[j]);
        hp[j] = h;
        lp[j] = f2b(vv[j] - b2f(h));
    }
    *(int2*)(hi + i) = hraw;
    *(int2*)(lo + i) = lraw;
}

// ---------------- fp32 [R][Cc] -> bf16 transposed [Cc][R] ----------------
__global__ __launch_bounds__(256)
void transpose_cvt(const float* __restrict__ in, bf16* __restrict__ out,
                   int R, int Cc)
{
    __shared__ bf16 t[32][33];
    int bx = blockIdx.x * 32;
    int by = blockIdx.y * 32;
    int tx = threadIdx.x;
    int ty = threadIdx.y;
    #pragma unroll
    for (int i=0;i<4;++i){
        int r = by + ty + i*8;
        int c = bx + tx;
        t[ty+i*8][tx] = f2b(in[(size_t)r*Cc + c]);
    }
    __syncthreads();
    #pragma unroll
    for (int i=0;i<4;++i){
        int r = bx + ty + i*8;
        int c = by + tx;
        out[(size_t)r*R + c] = t[tx][ty+i*8];
    }
}

// ---- GEMM, block tile 128x256, wave tile 64x128 (mi4 x ni8) ----
// Round-10: global_load_lds staging (width 16), linear LDS (stride 32 = BK),
// XOR slot swizzle p = q ^ ((row>>2)&3) applied on BOTH the global source
// (inverse) and the ds_read side (rule #21). 16-lane read groups then cover
// all 8 16B bank-positions exactly 2x -> conflict-free.
// A[M][K] (+optional lo) x Bt[N][K] -> C[M][N] + bias. N%256==0, K%32==0.
template<typename OutT, bool SPLIT>
__global__ __launch_bounds__(256,2)
void gemm_wide(const bf16* __restrict__ A, const bf16* __restrict__ Alo,
               const bf16* __restrict__ Bt, const float* __restrict__ bias,
               OutT* __restrict__ C, int M, int N, int K)
{
    __shared__ bf16 As[128*32];
    __shared__ bf16 Als[SPLIT ? 128*32 : 8];
    __shared__ bf16 Bs[256*32];

    int tid  = threadIdx.x;
    int lane = tid & 63, wave = tid >> 6;
    int wm = (wave>>1)*64, wn = (wave&1)*128;
    int bm = blockIdx.y*128, bn = blockIdx.x*256;
    int lrow = lane & 15;
    int quad = lane >> 4;
    int sw8  = (quad ^ ((lrow>>2)&3)) * 8;   // swizzled element offset for frag reads

    f32x4 acc[4][8] = {};

    for (int k0 = 0; k0 < K; k0 += 32) {
        // ---- stage A (+Alo): 8KB each, 2 calls/wave ----
        #pragma unroll
        for (int it=0; it<2; ++it) {
            int o  = (wave*2+it)*1024 + lane*16;  // LDS byte offset this lane lands at
            int r  = o >> 6;                      // row 0..127
            int p  = (o >> 4) & 3;                // physical 16B slot in row
            int ls = p ^ ((r>>2)&3);              // logical slot to fetch
            int ga = bm + r; if (ga >= M) ga = M-1;
            gl_lds16(A + (size_t)ga*K + k0 + ls*8, &As[(wave*2+it)*512]);
            if constexpr (SPLIT)
                gl_lds16(Alo + (size_t)ga*K + k0 + ls*8, &Als[(wave*2+it)*512]);
        }
        // ---- stage B: 16KB, 4 calls/wave ----
        #pragma unroll
        for (int it=0; it<4; ++it) {
            int o  = (wave*4+it)*1024 + lane*16;
            int r  = o >> 6;                      // row 0..255
            int p  = (o >> 4) & 3;
            int ls = p ^ ((r>>2)&3);
            gl_lds16(Bt + (size_t)(bn + r)*K + k0 + ls*8, &Bs[(wave*4+it)*512]);
        }
        __syncthreads();   // compiler drains vmcnt(0) here: staging visible

        bf16x8 b[8];
        #pragma unroll
        for (int i=0;i<8;++i)
            b[i] = *(const bf16x8*)(&Bs[(wn+i*16+lrow)*32 + sw8]);
        #pragma unroll
        for (int mi=0;mi<4;++mi){
            bf16x8 a = *(const bf16x8*)(&As[(wm+mi*16+lrow)*32 + sw8]);
            #pragma unroll
            for (int ni=0;ni<8;++ni)
                acc[mi][ni] = MFMA(a, b[ni], acc[mi][ni]);
            if constexpr (SPLIT) {
                bf16x8 al = *(const bf16x8*)(&Als[(wm+mi*16+lrow)*32 + sw8]);
                #pragma unroll
                for (int ni=0;ni<8;++ni)
                    acc[mi][ni] = MFMA(al, b[ni], acc[mi][ni]);
            }
        }
        __syncthreads();   // reads done before next iteration's staging overwrites
    }

    #pragma unroll
    for (int ni=0;ni<8;++ni){
        int col = bn + wn + ni*16 + lrow;
        float bv = bias[col];
        #pragma unroll
        for (int mi=0;mi<4;++mi){
            int rowb = bm + wm + mi*16 + quad*4;
            #pragma unroll
            for (int r=0;r<4;++r){
                int row = rowb + r;
                if (row < M) {
                    float v = acc[mi][ni][r] + bv;
                    if constexpr (sizeof(OutT)==4) C[(size_t)row*N + col] = v;
                    else                           C[(size_t)row*N + col] = f2b(v);
                }
            }
        }
    }
}

// ---------------- RoPE in-place on q,k (pure rotation) ----------------
__global__ __launch_bounds__(256)
void rope_kernel(bf16* __restrict__ qkv, const float* __restrict__ rope)
{
    int idx = blockIdx.x*256 + threadIdx.x;
    int d = idx & 31;
    int h = (idx >> 5) & 15;
    int m = idx >> 9;
    if (m >= M_) return;
    int l = m % L_;
    if (l < NREG_) return;
    const float* cp = rope + (size_t)(l - NREG_)*D_;
    const float* sp = rope + (size_t)(L_ - NREG_)*D_ + (size_t)(l - NREG_)*D_;
    float c0 = cp[d], c1 = cp[d+32], s0 = sp[d], s1 = sp[d+32];
    size_t base = (size_t)m*3072 + h*64;
    {
        float a = b2f(qkv[base + d]), b = b2f(qkv[base + d + 32]);
        qkv[base + d]      = f2b(a*c0 - b*s0);
        qkv[base + d + 32] = f2b(b*c1 + a*s1);
    }
    {
        size_t kb = base + 1024;
        float a = b2f(qkv[kb + d]), b = b2f(qkv[kb + d + 32]);
        qkv[kb + d]      = f2b(a*c0 - b*s0);
        qkv[kb + d + 32] = f2b(b*c1 + a*s1);
    }
}

// ---------------- V -> Vt [B*H][D][LP_] (zero-padded cols) ----------------
__global__ __launch_bounds__(256)
void transpose_v(const bf16* __restrict__ qkv, bf16* __restrict__ Vt)
{
    __shared__ bf16 t[64*72];
    int bh = blockIdx.y, lt = blockIdx.x;
    int b = bh >> 4, h = bh & 15;
    int tid = threadIdx.x;
    #pragma unroll
    for (int it=0; it<2; ++it){
        int i = tid + it*256;
        int il = i >> 3, c = (i&7)*8;
        int l = lt*64 + il;
        int4 v = {0,0,0,0};
        if (l < L_) v = *(const int4*)(qkv + ((size_t)b*L_ + l)*3072 + 2048 + h*64 + c);
        *(int4*)(&t[il*72 + c]) = v;
    }
    __syncthreads();
    #pragma unroll
    for (int it=0; it<2; ++it){
        int i = tid + it*256;
        int d = i >> 3, ck = (i&7)*8;
        if (lt*64 + ck + 8 <= LP_){
            union { int4 q; bf16 e[8]; } u;
            #pragma unroll
            for (int j=0;j<8;++j) u.e[j] = t[(ck+j)*72 + d];
            *(int4*)(&Vt[((size_t)bh*64 + d)*LP_ + lt*64 + ck]) = u.q;
        }
    }
}

// ---------------- flash attention (round-9: register-resident P) ----------------
// PV computed operand-swapped, MFMA(V^T-frag, P-as-B-frag); permuted K staging
// makes each lane's 8 P keys lane-local. lsum via MFMA(ones, P) matches the O^T
// accumulator layout exactly.
__global__ __launch_bounds__(256)
void attn_kernel(const bf16* __restrict__ qkv, const bf16* __restrict__ Vt,
                 float* __restrict__ out)
{
    __shared__ bf16 sQ[128*72];   // Q tile [128][72]
    __shared__ bf16 sK[64*72];    // [key-slot][d], rows permuted
    __shared__ bf16 sV[64*72];    // [d][key]

    int tid = threadIdx.x, lane = tid & 63, wave = tid >> 6;
    int lrow = lane & 15, lk8 = (lane>>4)*8, quad = lane >> 4;
    int qt = blockIdx.x, bh = blockIdx.y;
    int b  = bh >> 4, h = bh & 15;
    size_t rowbase = (size_t)b * L_;
    int q0 = qt * 128;

    #pragma unroll
    for (int it=0; it<4; ++it){
        int i = tid + it*256;
        int r = i >> 3;
        int c = (i & 7) * 8;
        int lq = q0 + r;
        int4 v = {0,0,0,0};
        if (lq < L_) v = *(const int4*)(qkv + (rowbase + lq)*3072 + h*64 + c);
        *(int4*)(&sQ[r*72 + c]) = v;
    }
    __syncthreads();

    bf16x8 qf[2][2];
    #pragma unroll
    for (int qi=0;qi<2;++qi)
        #pragma unroll
        for (int s=0;s<2;++s)
            qf[qi][s] = *(const bf16x8*)(&sQ[(wave*32 + qi*16 + lrow)*72 + s*32 + lk8]);

    f32x4 o_[2][4] = {};
    f32x4 lsum[2] = {};

    bf16x8 onesf;
    #pragma unroll
    for (int j=0;j<8;++j) onesf[j] = (short)0x3F80;   // bf16 1.0

    const int nkt = (L_ + 63) / 64;   // 33

    int4 kr[2], vr[2];
    {
        #pragma unroll
        for (int it=0; it<2; ++it){
            int i = tid + it*256;
            int r = i >> 3, c = (i & 7)*8;
            int pr = (r & 0x23) | ((r & 0x0C) << 1) | ((r & 0x10) >> 2); // slot->key
            kr[it] = *(const int4*)(qkv + (rowbase + pr)*3072 + 1024 + h*64 + c);
            vr[it] = *(const int4*)(Vt + ((size_t)bh*64 + r)*LP_ + c);
        }
    }

    for (int kt = 0; kt < nkt; ++kt) {
        __syncthreads();
        #pragma unroll
        for (int it=0; it<2; ++it){
            int i = tid + it*256;
            int r = i >> 3, c = (i & 7)*8;
            *(int4*)(&sK[r*72 + c]) = kr[it];
            *(int4*)(&sV[r*72 + c]) = vr[it];
        }
        __syncthreads();
        if (kt+1 < nkt){
            #pragma unroll
            for (int it=0; it<2; ++it){
                int i = tid + it*256;
                int r = i >> 3, c = (i & 7)*8;
                int pr = (r & 0x23) | ((r & 0x0C) << 1) | ((r & 0x10) >> 2);
                int lk = (kt+1)*64 + pr;
                kr[it] = (lk < L_) ? *(const int4*)(qkv + (rowbase+lk)*3072 + 1024 + h*64 + c)
                                   : (int4){0,0,0,0};
                int vc = (kt+1)*64 + c;
                vr[it] = (vc + 8 <= LP_) ? *(const int4*)(Vt + ((size_t)bh*64 + r)*LP_ + vc)
                                         : (int4){0,0,0,0};
            }
        }

        bool full = (kt != 32);
        int4 pb[2][2];   // P as B-fragments: [qi][s], lane-local 8 keys each

        #pragma unroll
        for (int ki=0; ki<4; ++ki){
            bf16x8 kf0 = *(const bf16x8*)(&sK[(ki*16+lrow)*72 + lk8]);
            bf16x8 kf1 = *(const bf16x8*)(&sK[(ki*16+lrow)*72 + 32 + lk8]);
            #pragma unroll
            for (int qi=0; qi<2; ++qi){
                f32x4 t = {};
                t = MFMA(kf0, qf[qi][0], t);
                t = MFMA(kf1, qf[qi][1], t);
                float p[4];
                #pragma unroll
                for (int r=0;r<4;++r){
                    float e = __builtin_amdgcn_exp2f(t[r]*QSC);
                    // actual key index under permuted staging:
                    int keyi = (ki>>1)*32 + quad*8 + (ki&1)*4 + r;
                    p[r] = (full || (2048 + keyi) < L_) ? e : 0.f;
                }
                union { int2 d2; __hip_bfloat162 h2[2]; } u;
                u.h2[0] = __float22bfloat162_rn({p[0], p[1]});
                u.h2[1] = __float22bfloat162_rn({p[2], p[3]});
                if ((ki & 1) == 0){ pb[qi][ki>>1].x = u.d2.x; pb[qi][ki>>1].y = u.d2.y; }
                else              { pb[qi][ki>>1].z = u.d2.x; pb[qi][ki>>1].w = u.d2.y; }
            }
        }

        #pragma unroll
        for (int ni=0; ni<4; ++ni){
            bf16x8 vf0 = *(const bf16x8*)(&sV[(ni*16+lrow)*72 + lk8]);
            bf16x8 vf1 = *(const bf16x8*)(&sV[(ni*16+lrow)*72 + 32 + lk8]);
            #pragma unroll
            for (int mi=0; mi<2; ++mi){
                f32x4 t = o_[mi][ni];
                t = MFMA(vf0, as8(pb[mi][0]), t);
                t = MFMA(vf1, as8(pb[mi][1]), t);
                o_[mi][ni] = t;
            }
        }
        #pragma unroll
        for (int mi=0; mi<2; ++mi){
            lsum[mi] = MFMA(onesf, as8(pb[mi][0]), lsum[mi]);
            lsum[mi] = MFMA(onesf, as8(pb[mi][1]), lsum[mi]);
        }
    }

    // O^T layout: lane holds q = lane&15 (within mi group), d = ni*16 + quad*4 + r
    #pragma unroll
    for (int mi=0; mi<2; ++mi){
        float inv = 1.f / lsum[mi][0];
        int lq = q0 + wave*32 + mi*16 + lrow;
        if (lq < L_){
            size_t base = (rowbase + lq)*1024 + h*64;
            #pragma unroll
            for (int ni=0; ni<4; ++ni){
                f32x4 t = o_[mi][ni];
                float4 w = {t[0]*inv, t[1]*inv, t[2]*inv, t[3]*inv};
                *(float4*)(&out[base + ni*16 + quad*4]) = w;
            }
        }
    }
}

// ---------------- LayerNorm (fp32 in) -> bf16 ----------------
__global__ __launch_bounds__(256)
void ln_kernel(const float* __restrict__ in, const float* __restrict__ gamma,
               const float* __restrict__ beta, bf16* __restrict__ y)
{
    int row = blockIdx.x;
    int tid = threadIdx.x;
    int wave = tid >> 6, lane = tid & 63;
    float4 v4 = *(const float4*)(in + (size_t)row*1024 + tid*4);
    float v[4] = {v4.x, v4.y, v4.z, v4.w};
    float s = 0.f, q = 0.f;
    #pragma unroll
    for (int j=0;j<4;++j){ s += v[j]; q += v[j]*v[j]; }
    #pragma unroll
    for (int o=1;o<64;o<<=1){ s += __shfl_xor(s, o); q += __shfl_xor(q, o); }
    __shared__ float sh[8];
    if (lane == 0){ sh[wave] = s; sh[4+wave] = q; }
    __syncthreads();
    s = sh[0]+sh[1]+sh[2]+sh[3];
    q = sh[4]+sh[5]+sh[6]+sh[7];
    float mu  = s * (1.f/1024.f);
    float var = q * (1.f/1024.f) - mu*mu;
    float rstd = rsqrtf(var + 1e-5f);
    int2 raw;
    bf16* ob = (bf16*)&raw;
    #pragma unroll
    for (int j=0;j<4;++j){
        float g = gamma[tid*4+j], be = beta[tid*4+j];
        ob[j] = f2b((v[j]-mu)*rstd*g + be);
    }
    *(int2*)(y + (size_t)row*1024 + tid*4) = raw;
}

// ---------------- launch ----------------
extern "C" void kernel_launch(void* const* d_in, const int* in_sizes, int n_in,
                              void* d_out, int out_size, void* d_ws, size_t ws_size,
                              hipStream_t stream)
{
    const float* x     = (const float*)d_in[0];
    const float* rope  = (const float*)d_in[1];
    const float* Wqkv  = (const float*)d_in[2];
    const float* bqkv  = (const float*)d_in[3];
    const float* Wproj = (const float*)d_in[4];
    const float* bproj = (const float*)d_in[5];
    const float* lng   = (const float*)d_in[6];
    const float* lnb   = (const float*)d_in[7];
    float* out = (float*)d_out;

    char* ws = (char*)d_ws;
    size_t off = 0;
    auto alloc = [&](size_t bytes)->char* {
        char* p = ws + off;
        off += (bytes + 255) & ~(size_t)255;
        return p;
    };
    bf16* xhi    = (bf16*)alloc((size_t)M_*C_*2);
    bf16* xlo    = (bf16*)alloc((size_t)M_*C_*2);
    bf16* WqkvT  = (bf16*)alloc((size_t)3*C_*C_*2);
    bf16* WprojT = (bf16*)alloc((size_t)C_*C_*2);
    bf16* qkv    = (bf16*)alloc((size_t)M_*3*C_*2);
    bf16* Vt     = (bf16*)alloc((size_t)B_*H_*D_*LP_*2);

    float* attnF = (float*)xhi;        // xhi+xlo region = exactly M*C*4 bytes
    bf16*  y     = qkv;                // qkv dead after attention

    cvt_split<<<M_*C_/1024, 256, 0, stream>>>(x, xhi, xlo, M_*C_);
    transpose_cvt<<<dim3(3*C_/32, C_/32), dim3(32,8), 0, stream>>>(Wqkv, WqkvT, C_, 3*C_);
    transpose_cvt<<<dim3(C_/32, C_/32), dim3(32,8), 0, stream>>>(Wproj, WprojT, C_, C_);
    gemm_wide<bf16, true><<<dim3(3*C_/256, (M_+127)/128), 256, 0, stream>>>(
        xhi, xlo, WqkvT, bqkv, qkv, M_, 3*C_, C_);
    rope_kernel<<<(M_*H_*32)/256, 256, 0, stream>>>(qkv, rope);
    transpose_v<<<dim3((L_+63)/64, B_*H_), 256, 0, stream>>>(qkv, Vt);
    attn_kernel<<<dim3((L_+127)/128, B_*H_), 256, 0, stream>>>(qkv, Vt, attnF);
    ln_kernel<<<M_, 256, 0, stream>>>(attnF, lng, lnb, y);
    gemm_wide<float, false><<<dim3(C_/256, (M_+127)/128), 256, 0, stream>>>(
        y, nullptr, WprojT, bproj, out, M_, C_, C_);
}